// Round 3
// baseline (835.059 us; speedup 1.0000x reference)
//
#include <hip/hip_runtime.h>
#include <hip/hip_bf16.h>

typedef unsigned short ushort_t;
typedef short short8 __attribute__((ext_vector_type(8)));
typedef float f32x4 __attribute__((ext_vector_type(4)));

#define J_TOT 43
#define J6 13
#define D_DIM 512
#define BT 3136
#define OUTW 168

__device__ __forceinline__ unsigned short bf16rne(float f) {
    unsigned u = __builtin_bit_cast(unsigned, f);
    u += 0x7fffu + ((u >> 16) & 1u);
    return (unsigned short)(u >> 16);
}

__device__ __forceinline__ float gelu_f(float v) {
    float t = v * __builtin_fmaf(v * v, 0.0356774081f, 0.7978845608f);
    float e = __builtin_amdgcn_exp2f(t * 2.8853900818f);   // e^{2t}
    float s = __builtin_amdgcn_rcpf(1.0f + e);
    return __builtin_fmaf(-v, s, v);                        // v - v/(1+e^{2t})
}

// ---------------- Pre-pass 1: W1 [J][d][e] fp32 -> W1t [J][e=n][d=k] bf16 -----
__global__ void w1_transpose_kernel(const float* __restrict__ W1, ushort_t* __restrict__ W1t) {
    __shared__ ushort_t tile[64][74];
    const int j = blockIdx.z;
    const int t = threadIdx.x;          // 256
    const int d0 = blockIdx.x * 64, e0 = blockIdx.y * 64;
    const float* src = W1 + (size_t)j * D_DIM * D_DIM;
    const int el = t & 63, dl = t >> 6;
#pragma unroll
    for (int i = 0; i < 16; i++) {
        int d = dl + i * 4;
        tile[el][d] = bf16rne(src[(size_t)(d0 + d) * D_DIM + e0 + el]);
    }
    __syncthreads();
    ushort_t* dst = W1t + (size_t)j * D_DIM * D_DIM;
#pragma unroll
    for (int i = 0; i < 16; i++) {
        int n = dl + i * 4;
        dst[(size_t)(e0 + n) * D_DIM + d0 + el] = tile[n][el];
    }
}

// ---------------- Pre-pass 2: W2 pack + b2 pack ------------------------------
__global__ void w2_pack_kernel(const float* __restrict__ W2a, const float* __restrict__ b2a,
                               const float* __restrict__ W2b, const float* __restrict__ b2b,
                               ushort_t* __restrict__ W2t, float* __restrict__ b2p) {
    const int j = blockIdx.x;
    const int t = threadIdx.x;
    const int odim = (j < J6) ? 6 : 3;
    const float* w = (j < J6) ? (W2a + (size_t)j * D_DIM * 6) : (W2b + (size_t)(j - J6) * D_DIM * 3);
    for (int idx = t; idx < 16 * D_DIM; idx += 256) {
        int o = idx >> 9, k = idx & 511;
        float v = (o < odim) ? w[(size_t)k * odim + o] : 0.0f;
        W2t[(size_t)j * 16 * D_DIM + idx] = bf16rne(v);
    }
    if (t < 16) {
        const float* bb = (j < J6) ? (b2a + (size_t)j * 6) : (b2b + (size_t)(j - J6) * 3);
        b2p[j * 16 + t] = (t < odim) ? bb[t] : 0.0f;
    }
}

// ---------------- Fused main kernel ------------------------------------------
// grid (25 m-tiles, 43 joints), block 256 = 4 waves, 1 block/CU (160 KB LDS).
// A (x tile, bf16) resident for full K=512 in LDS; B (W1t) register-prefetched
// 2 rounds ahead -> ds_write double buffer. No global_load_lds => no vmcnt(0)
// drain at barriers => real pipelining.
__global__ __launch_bounds__(256, 1)
void md_main(const float* __restrict__ x,
             const float* __restrict__ b1,
             const ushort_t* __restrict__ W1t,
             const ushort_t* __restrict__ W2t,
             const float* __restrict__ b2p,
             float* __restrict__ out) {
    __shared__ unsigned char smem[163840];
    char* const As = (char*)smem;                 // [128 m][64 ch] sw=ch^(m&63), 128 KB
    char* const B0 = (char*)smem + 131072;        // [128 n][8 ch]  sw=ch^(n&7), 16 KB
    char* const B1 = (char*)smem + 147456;        // 16 KB
    char* const Hs = (char*)smem + 131072;        // h: [128 m][16 ch] sw=c^(m&15), 32 KB (alias B0+B1)

    const int j   = blockIdx.y;
    const int m0  = blockIdx.x * 128;
    const int tid = threadIdx.x;
    const int lane = tid & 63;
    const int wid  = tid >> 6;
    const int wrow = (wid >> 1) * 64;
    const int wcol = (wid & 1) * 64;
    const int quad = lane >> 4;
    const int l16  = lane & 15;

    const ushort_t* w1j = W1t + (size_t)j * D_DIM * D_DIM;
    const ushort_t* w2j = W2t + (size_t)j * 16 * D_DIM;

    // ---- B prefetch mapping: thread -> row n = tid>>1, chunks (tid&1)*4 + c --
    const int bn  = tid >> 1;
    const int bc0 = (tid & 1) * 4;
    const ushort_t* bsrc = w1j + (size_t)bn * D_DIM + bc0 * 8;  // + g's offset
    int bws[4];
#pragma unroll
    for (int c = 0; c < 4; c++) bws[c] = bn * 128 + (((bc0 + c) ^ (bn & 7)) * 16);

    uint4 pa[4], pb[4];
#define ISSUE_B(g, p)                                                             \
    {                                                                             \
        const ushort_t* s_ = bsrc + (size_t)((g) >> 3) * 128 * D_DIM + ((g) & 7) * 64; \
        p[0] = *(const uint4*)(s_);      p[1] = *(const uint4*)(s_ + 8);          \
        p[2] = *(const uint4*)(s_ + 16); p[3] = *(const uint4*)(s_ + 24);         \
    }
#define WRITE_B(dst, p)                                                           \
    {                                                                             \
        *(uint4*)((dst) + bws[0]) = p[0]; *(uint4*)((dst) + bws[1]) = p[1];       \
        *(uint4*)((dst) + bws[2]) = p[2]; *(uint4*)((dst) + bws[3]) = p[3];       \
    }

    ISSUE_B(0, pa);
    ISSUE_B(1, pb);

    // ---- A stage: fp32 x -> bf16 -> LDS (once). thread -> row tid>>1, half tid&1
    {
        const int ar = tid >> 1;
        const int ap = tid & 1;                   // 256 floats each
        int arow = m0 + ar; if (arow > BT - 1) arow = BT - 1;
        const float4* xr4 = (const float4*)(x + ((size_t)arow * J_TOT + j) * D_DIM + ap * 256);
        char* arow_base = As + ar * 1024;
        const int asw = ar & 63;
#pragma unroll
        for (int b = 0; b < 8; b++) {
            float4 f[8];
#pragma unroll
            for (int i = 0; i < 8; i++) f[i] = xr4[b * 8 + i];
#pragma unroll
            for (int i = 0; i < 4; i++) {
                union { unsigned short s[8]; uint4 v; } pk;
                float4 u0 = f[2 * i], u1 = f[2 * i + 1];
                pk.s[0] = bf16rne(u0.x); pk.s[1] = bf16rne(u0.y);
                pk.s[2] = bf16rne(u0.z); pk.s[3] = bf16rne(u0.w);
                pk.s[4] = bf16rne(u1.x); pk.s[5] = bf16rne(u1.y);
                pk.s[6] = bf16rne(u1.z); pk.s[7] = bf16rne(u1.w);
                int ch = ap * 32 + b * 4 + i;
                *(uint4*)(arow_base + ((ch ^ asw) * 16)) = pk.v;
            }
        }
    }

    f32x4 acc2[4];
#pragma unroll
    for (int r = 0; r < 4; r++) acc2[r] = (f32x4){0.f, 0.f, 0.f, 0.f};

    for (int nt = 0; nt < 4; nt++) {
        const int n0 = nt * 128;
        f32x4 acc[4][4];
#pragma unroll
        for (int a = 0; a < 4; a++)
#pragma unroll
            for (int b = 0; b < 4; b++) acc[a][b] = (f32x4){0.f, 0.f, 0.f, 0.f};

        // pipeline entry: pa = B(nt,0), pb = B(nt,1) already in flight
        WRITE_B(B0, pa);
#pragma unroll
        for (int c = 0; c < 4; c++) pa[c] = pb[c];
        ISSUE_B(nt * 8 + 2, pb);
        __syncthreads();                           // A (nt==0) + B0 visible

        for (int ks = 0; ks < 8; ks++) {
            char* const bcur = (ks & 1) ? B1 : B0;
            // ---- compute: 2 x (4 a-frags, 4 b-frags, 16 MFMA), A from full-K LDS
#pragma unroll
            for (int kk = 0; kk < 2; kk++) {
                short8 af[4], bfr[4];
                const int cha = ks * 8 + kk * 4 + quad;
                const int chb = kk * 4 + quad;
#pragma unroll
                for (int rt = 0; rt < 4; rt++) {
                    int m = wrow + rt * 16 + l16;
                    af[rt] = *(const short8*)(As + m * 1024 + ((cha ^ (m & 63)) * 16));
                }
#pragma unroll
                for (int ct = 0; ct < 4; ct++) {
                    int n = wcol + ct * 16 + l16;
                    bfr[ct] = *(const short8*)(bcur + n * 128 + ((chb ^ (n & 7)) * 16));
                }
#pragma unroll
                for (int rt = 0; rt < 4; rt++)
#pragma unroll
                    for (int ct = 0; ct < 4; ct++)
                        acc[rt][ct] = __builtin_amdgcn_mfma_f32_16x16x32_bf16(
                            af[rt], bfr[ct], acc[rt][ct], 0, 0, 0);
            }
            if (ks < 7) {
                WRITE_B(((ks + 1) & 1) ? B1 : B0, pa);
#pragma unroll
                for (int c = 0; c < 4; c++) pa[c] = pb[c];
                int g = nt * 8 + ks + 3;
                if (g < 32) ISSUE_B(g, pb);
            }
            __syncthreads();
        }

        // ---- bias + GELU -> h (bf16) into Hs (aliases B0/B1)
#pragma unroll
        for (int ct = 0; ct < 4; ct++) {
            int ncol = wcol + ct * 16 + l16;
            float bv = b1[j * D_DIM + n0 + ncol];
            int c2 = ncol >> 3;
            int boff2 = (ncol & 7) * 2;
#pragma unroll
            for (int rt = 0; rt < 4; rt++) {
                int mb = wrow + rt * 16 + quad * 4;
#pragma unroll
                for (int r = 0; r < 4; r++) {
                    float g = gelu_f(acc[rt][ct][r] + bv);
                    int m = mb + r;
                    *(unsigned short*)(Hs + m * 256 + ((c2 ^ (m & 15)) * 16) + boff2) = bf16rne(g);
                }
            }
        }
        __syncthreads();

        // ---- layer 2: waves 0,1 handle rows 0-63 / 64-127, K = this 128-col slab
        if (wid < 2) {
            short8 wf[4];
#pragma unroll
            for (int kk2 = 0; kk2 < 4; kk2++) {
                const ushort_t* gsrc = w2j + (size_t)l16 * D_DIM + n0 + kk2 * 32 + quad * 8;
                wf[kk2] = *(const short8*)gsrc;
            }
#pragma unroll
            for (int rt = 0; rt < 4; rt++) {
                int m = wid * 64 + rt * 16 + l16;
#pragma unroll
                for (int kk2 = 0; kk2 < 4; kk2++) {
                    int ch = kk2 * 4 + quad;
                    short8 a2 = *(const short8*)(Hs + m * 256 + ((ch ^ (m & 15)) * 16));
                    acc2[rt] = __builtin_amdgcn_mfma_f32_16x16x32_bf16(a2, wf[kk2], acc2[rt], 0, 0, 0);
                }
            }
        }
        __syncthreads();   // h reads done before next nt's WRITE_B into B0
    }

    // ---- epilogue
    if (wid < 2) {
        int o = l16;
        int odim = (j < J6) ? 6 : 3;
        int cb = (j < J6) ? j * 6 : 78 + (j - J6) * 3;
        float bo = b2p[j * 16 + o];
        if (o < odim) {
#pragma unroll
            for (int rt = 0; rt < 4; rt++) {
#pragma unroll
                for (int r = 0; r < 4; r++) {
                    int m = m0 + wid * 64 + rt * 16 + quad * 4 + r;
                    if (m < BT) out[(size_t)m * OUTW + cb + o] = acc2[rt][r] + bo;
                }
            }
        }
    }
#undef ISSUE_B
#undef WRITE_B
}

extern "C" void kernel_launch(void* const* d_in, const int* in_sizes, int n_in,
                              void* d_out, int out_size, void* d_ws, size_t ws_size,
                              hipStream_t stream) {
    const float* x   = (const float*)d_in[0];
    const float* W1  = (const float*)d_in[1];
    const float* b1  = (const float*)d_in[2];
    const float* W2a = (const float*)d_in[3];
    const float* b2a = (const float*)d_in[4];
    const float* W2b = (const float*)d_in[5];
    const float* b2b = (const float*)d_in[6];
    float* out = (float*)d_out;

    ushort_t* W1t = (ushort_t*)d_ws;                            // 22,544,384 B
    ushort_t* W2t = W1t + (size_t)J_TOT * D_DIM * D_DIM;        //    704,512 B
    float*    b2p = (float*)(W2t + (size_t)J_TOT * 16 * D_DIM); //      2,752 B

    w1_transpose_kernel<<<dim3(8, 8, J_TOT), 256, 0, stream>>>(W1, W1t);
    w2_pack_kernel<<<J_TOT, 256, 0, stream>>>(W2a, b2a, W2b, b2b, W2t, b2p);
    md_main<<<dim3(25, J_TOT), 256, 0, stream>>>(x, b1, W1t, W2t, b2p, out);
}